// Round 1
// baseline (902.439 us; speedup 1.0000x reference)
//
#include <hip/hip_runtime.h>

#define NF 128

__device__ __forceinline__ unsigned okey(float f) {
  unsigned u = __float_as_uint(f);
  return (u & 0x80000000u) ? ~u : (u | 0x80000000u);
}

// ---------- prep: 1/||p||, transpose W_lin ----------
__global__ void prep_kernel(const float* __restrict__ p, const float* __restrict__ W_lin,
                            float* __restrict__ pninv, float* __restrict__ wlt) {
  __shared__ float red[128];
  int t = threadIdx.x;  // 256
  if (t < 128) { float v = p[t]; red[t] = v * v; }
  __syncthreads();
  for (int s = 64; s > 0; s >>= 1) {
    if (t < s) red[t] += red[t + s];
    __syncthreads();
  }
  if (t == 0) pninv[0] = 1.0f / sqrtf(red[0]);
  for (int i = t; i < NF * NF; i += 256) {
    int r = i >> 7, c = i & 127;
    wlt[c * NF + r] = W_lin[i];
  }
}

// ---------- scores: one wave per row ----------
__global__ void score_kernel(const float* __restrict__ x, const float* __restrict__ p,
                             const float* __restrict__ pninv, float* __restrict__ score,
                             unsigned* __restrict__ keys, int n) {
  int wib = threadIdx.x >> 6, lane = threadIdx.x & 63;
  int r = blockIdx.x * 4 + wib;
  if (r >= n) return;
  float2 xv = *(const float2*)&x[(size_t)r * NF + lane * 2];
  float2 pv = *(const float2*)&p[lane * 2];
  float d = xv.x * pv.x + xv.y * pv.y;
#pragma unroll
  for (int off = 32; off > 0; off >>= 1) d += __shfl_down(d, off, 64);
  if (lane == 0) {
    float s = tanhf(d * pninv[0]);
    score[r] = s;
    keys[r] = okey(s);
  }
}

// ---------- top-128 radix select + stable sort, single block ----------
#define TK 128
#define LBCAP 2048
__global__ __launch_bounds__(1024) void topk_kernel(const unsigned* __restrict__ keys,
                                                    const float* __restrict__ score, int n,
                                                    int* __restrict__ perm, float* __restrict__ tsc) {
  __shared__ unsigned hist[256];
  __shared__ unsigned sh_prefix;
  __shared__ int sh_remaining;
  __shared__ int cntA, cntB;
  __shared__ unsigned selKey[TK];
  __shared__ int selIdx[TK];
  __shared__ int lbIdx[LBCAP];
  int t = threadIdx.x;
  if (t == 0) { sh_prefix = 0u; sh_remaining = TK; }
  for (int pos = 24; pos >= 0; pos -= 8) {
    if (t < 256) hist[t] = 0u;
    __syncthreads();
    unsigned pref = sh_prefix;
    unsigned hmask = (pos == 24) ? 0u : (0xFFFFFFFFu << (pos + 8));
    for (int i = t; i < n; i += 1024) {
      unsigned k = keys[i];
      if ((k & hmask) == pref) atomicAdd(&hist[(k >> pos) & 255], 1u);
    }
    __syncthreads();
    if (t == 0) {
      int rem = sh_remaining;
      unsigned c = 0;
      for (int b = 255; b >= 0; --b) {
        unsigned h = hist[b];
        if (c + h >= (unsigned)rem) {
          sh_prefix = pref | ((unsigned)b << pos);
          sh_remaining = rem - (int)c;
          break;
        }
        c += h;
      }
    }
    __syncthreads();
  }
  unsigned T = sh_prefix;
  int needEq = sh_remaining;
  if (t == 0) { cntA = 0; cntB = 0; }
  __syncthreads();
  for (int i = t; i < n; i += 1024) {
    unsigned k = keys[i];
    if (k > T) {
      int s = atomicAdd(&cntA, 1);
      if (s < TK) { selKey[s] = k; selIdx[s] = i; }
    } else if (k == T) {
      int s = atomicAdd(&cntB, 1);
      if (s < LBCAP) lbIdx[s] = i;
    }
  }
  __syncthreads();
  int nA = cntA;  // == TK - needEq
  int nb = cntB < LBCAP ? cntB : LBCAP;
  for (int ii = t; ii < nb; ii += 1024) {
    int my = lbIdx[ii];
    int rank = 0;
    for (int j = 0; j < nb; ++j) rank += (lbIdx[j] < my) ? 1 : 0;
    if (rank < needEq) { selKey[nA + rank] = T; selIdx[nA + rank] = my; }
  }
  __syncthreads();
  if (t < TK) {
    unsigned mk = selKey[t];
    int mi = selIdx[t];
    int rank = 0;
    for (int j = 0; j < TK; ++j) {
      unsigned kj = selKey[j];
      int ij = selIdx[j];
      rank += (kj > mk || (kj == mk && ij < mi)) ? 1 : 0;
    }
    perm[rank] = mi;
    tsc[rank] = score[mi];
  }
}

// ---------- GRU: block per row i, thread per col j ----------
__global__ void gru_kernel(const float* __restrict__ x, const int* __restrict__ perm,
                           const float* __restrict__ tsc, const float* __restrict__ W0,
                           const float* __restrict__ w_ih, const float* __restrict__ w_hh,
                           const float* __restrict__ b_ih, const float* __restrict__ b_hh,
                           float* __restrict__ W) {
  __shared__ float xs[NF], w0s[NF];
  int i = blockIdx.x, j = threadIdx.x;
  int pi = perm[i];
  float s = tsc[i];
  xs[j] = x[(size_t)pi * NF + j] * s;
  w0s[j] = W0[i * NF + j];
  __syncthreads();
  float gir = b_ih[j], giz = b_ih[NF + j], gin = b_ih[2 * NF + j];
  float ghr = b_hh[j], ghz = b_hh[NF + j], ghn = b_hh[2 * NF + j];
  const float* wr = w_ih + (size_t)j * NF;
  const float* wz = w_ih + (size_t)(NF + j) * NF;
  const float* wn = w_ih + (size_t)(2 * NF + j) * NF;
  const float* ur = w_hh + (size_t)j * NF;
  const float* uz = w_hh + (size_t)(NF + j) * NF;
  const float* un = w_hh + (size_t)(2 * NF + j) * NF;
#pragma unroll 4
  for (int k = 0; k < NF; ++k) {
    float xv = xs[k], wv = w0s[k];
    gir = fmaf(xv, wr[k], gir);
    giz = fmaf(xv, wz[k], giz);
    gin = fmaf(xv, wn[k], gin);
    ghr = fmaf(wv, ur[k], ghr);
    ghz = fmaf(wv, uz[k], ghz);
    ghn = fmaf(wv, un[k], ghn);
  }
  float r = 1.0f / (1.0f + expf(-(gir + ghr)));
  float z = 1.0f / (1.0f + expf(-(giz + ghz)));
  float nn = tanhf(gin + r * ghn);
  W[i * NF + j] = (1.0f - z) * nn + z * w0s[j];
}

// ---------- degree ----------
__global__ void deg_init_kernel(float* __restrict__ deg, int n) {
  int i = blockIdx.x * blockDim.x + threadIdx.x;
  if (i < n) deg[i] = 1.0f;  // self-loop weight
}
__global__ void deg_scatter_kernel(const int* __restrict__ ei, const float* __restrict__ ew,
                                   float* __restrict__ deg, int E) {
  int e = blockIdx.x * blockDim.x + threadIdx.x;
  if (e < E) unsafeAtomicAdd(&deg[ei[E + e]], ew[e]);
}
__global__ void dinv_kernel(const float* __restrict__ deg, float* __restrict__ dinv, int n) {
  int i = blockIdx.x * blockDim.x + threadIdx.x;
  if (i < n) {
    float d = deg[i];
    dinv[i] = (d > 0.0f) ? rsqrtf(d) : 0.0f;
  }
}

// ---------- GEMM: C[r,c] = sum_k op(A[r,k]) * B[k,c] (+bias), B is 128x128 ----------
template <int RELU, int BIAS>
__global__ __launch_bounds__(256) void gemm128_kernel(const float* __restrict__ A,
                                                      const float* __restrict__ Bm,
                                                      const float* __restrict__ bias,
                                                      float* __restrict__ C, int nrows) {
  __shared__ float Bs[64][128];
  __shared__ float As[64][68];  // [k][r], padded
  const int t = threadIdx.x;
  const int ct = t & 31;   // 4-col group
  const int rt = t >> 5;   // 0..7 -> rows rt*8..rt*8+7
  const int row0 = blockIdx.x * 64;
  float4 acc[8];
#pragma unroll
  for (int j = 0; j < 8; ++j) acc[j] = make_float4(0.f, 0.f, 0.f, 0.f);

  for (int ph = 0; ph < 2; ++ph) {
    // stage B rows [ph*64, ph*64+64)
    {
      const float4* B4 = (const float4*)(Bm + ph * 64 * NF);
#pragma unroll
      for (int pp = 0; pp < 8; ++pp) {
        int idx = pp * 256 + t;  // 0..2047
        int k = idx >> 5, c4 = idx & 31;
        *((float4*)&Bs[k][c4 * 4]) = B4[idx];
      }
    }
    // stage A rows [row0,row0+64), cols [ph*64, ph*64+64), transposed
    {
#pragma unroll
      for (int pp = 0; pp < 4; ++pp) {
        int idx = pp * 256 + t;  // 0..1023
        int r = idx >> 4;        // 0..63
        int k4 = idx & 15;       // col group
        int gr = row0 + r;
        float4 v = make_float4(0.f, 0.f, 0.f, 0.f);
        if (gr < nrows) v = *((const float4*)&A[(size_t)gr * NF + ph * 64 + k4 * 4]);
        if (RELU) {
          v.x = fmaxf(v.x, 0.f); v.y = fmaxf(v.y, 0.f);
          v.z = fmaxf(v.z, 0.f); v.w = fmaxf(v.w, 0.f);
        }
        As[k4 * 4 + 0][r] = v.x;
        As[k4 * 4 + 1][r] = v.y;
        As[k4 * 4 + 2][r] = v.z;
        As[k4 * 4 + 3][r] = v.w;
      }
    }
    __syncthreads();
#pragma unroll 4
    for (int k = 0; k < 64; ++k) {
      float4 b = *((const float4*)&Bs[k][ct * 4]);
      float a[8];
      *((float4*)&a[0]) = *((const float4*)&As[k][rt * 8]);
      *((float4*)&a[4]) = *((const float4*)&As[k][rt * 8 + 4]);
#pragma unroll
      for (int j = 0; j < 8; ++j) {
        acc[j].x = fmaf(a[j], b.x, acc[j].x);
        acc[j].y = fmaf(a[j], b.y, acc[j].y);
        acc[j].z = fmaf(a[j], b.z, acc[j].z);
        acc[j].w = fmaf(a[j], b.w, acc[j].w);
      }
    }
    __syncthreads();
  }
  float4 bv = make_float4(0.f, 0.f, 0.f, 0.f);
  if (BIAS) bv = *((const float4*)&bias[ct * 4]);
#pragma unroll
  for (int j = 0; j < 8; ++j) {
    int gr = row0 + rt * 8 + j;
    if (gr < nrows) {
      float4 o = acc[j];
      if (BIAS) { o.x += bv.x; o.y += bv.y; o.z += bv.z; o.w += bv.w; }
      *((float4*)&C[(size_t)gr * NF + ct * 4]) = o;
    }
  }
}

// ---------- h init: self-loop term ----------
__global__ void hinit_kernel(const float* __restrict__ xw, const float* __restrict__ dinv,
                             float* __restrict__ h, int n) {
  int tid = blockIdx.x * blockDim.x + threadIdx.x;  // over n*32 float4s
  if (tid >= n * 32) return;
  int i = tid >> 5;
  float dv = dinv[i];
  float c = dv * dv;
  float4 v = ((const float4*)xw)[tid];
  v.x *= c; v.y *= c; v.z *= c; v.w *= c;
  ((float4*)h)[tid] = v;
}

// ---------- edge scatter: one wave per edge ----------
__global__ void edge_scatter_kernel(const int* __restrict__ ei, const float* __restrict__ ew,
                                    const float* __restrict__ dinv, const float* __restrict__ xw,
                                    float* __restrict__ h, int E) {
  int gw = (int)((blockIdx.x * (size_t)blockDim.x + threadIdx.x) >> 6);
  int lane = threadIdx.x & 63;
  if (gw >= E) return;
  int r = ei[gw];
  int c = ei[E + gw];
  float coef = dinv[r] * ew[gw] * dinv[c];
  float2 xv = *((const float2*)&xw[(size_t)r * NF + lane * 2]);
  float* hp = &h[(size_t)c * NF + lane * 2];
  unsafeAtomicAdd(hp, coef * xv.x);
  unsafeAtomicAdd(hp + 1, coef * xv.y);
}

extern "C" void kernel_launch(void* const* d_in, const int* in_sizes, int n_in,
                              void* d_out, int out_size, void* d_ws, size_t ws_size,
                              hipStream_t stream) {
  const float* x = (const float*)d_in[0];
  const int* ei = (const int*)d_in[1];
  const float* ew = (const float*)d_in[2];
  const float* p = (const float*)d_in[3];
  const float* w_ih = (const float*)d_in[4];
  const float* w_hh = (const float*)d_in[5];
  const float* b_ih = (const float*)d_in[6];
  const float* b_hh = (const float*)d_in[7];
  const float* W0 = (const float*)d_in[8];
  const float* W_lin = (const float*)d_in[9];
  const float* b_lin = (const float*)d_in[10];
  float* out = (float*)d_out;

  const int N = in_sizes[0] / NF;  // 50000
  const int E = in_sizes[1] / 2;   // 800000

  char* w = (char*)d_ws;
  float* xw = (float*)w;                                   // N*128
  float* score = (float*)(w + (size_t)N * NF * 4);         // N
  unsigned* keys = (unsigned*)((char*)score + (size_t)N * 4);
  float* deg = (float*)((char*)keys + (size_t)N * 4);
  float* dinv = (float*)((char*)deg + (size_t)N * 4);
  float* Wev = (float*)((char*)dinv + (size_t)N * 4);      // 128*128
  float* wlt = Wev + NF * NF;                              // 128*128
  int* perm = (int*)(wlt + NF * NF);                       // 128
  float* tsc = (float*)(perm + NF);                        // 128
  float* pninv = tsc + NF;                                 // 1

  prep_kernel<<<1, 256, 0, stream>>>(p, W_lin, pninv, wlt);
  score_kernel<<<(N + 3) / 4, 256, 0, stream>>>(x, p, pninv, score, keys, N);
  topk_kernel<<<1, 1024, 0, stream>>>(keys, score, N, perm, tsc);
  gru_kernel<<<NF, NF, 0, stream>>>(x, perm, tsc, W0, w_ih, w_hh, b_ih, b_hh, Wev);
  deg_init_kernel<<<(N + 255) / 256, 256, 0, stream>>>(deg, N);
  deg_scatter_kernel<<<(E + 255) / 256, 256, 0, stream>>>(ei, ew, deg, E);
  dinv_kernel<<<(N + 255) / 256, 256, 0, stream>>>(deg, dinv, N);
  gemm128_kernel<0, 0><<<(N + 63) / 64, 256, 0, stream>>>(x, Wev, nullptr, xw, N);
  hinit_kernel<<<(N * 32 + 255) / 256, 256, 0, stream>>>(xw, dinv, out, N);
  edge_scatter_kernel<<<(E + 3) / 4, 256, 0, stream>>>(ei, ew, dinv, xw, out, E);
  gemm128_kernel<1, 1><<<(N + 63) / 64, 256, 0, stream>>>(out, wlt, b_lin, out, N);
}

// Round 2
// 407.500 us; speedup vs baseline: 2.2146x; 2.2146x over previous
//
#include <hip/hip_runtime.h>

#define NF 128

__device__ __forceinline__ unsigned okey(float f) {
  unsigned u = __float_as_uint(f);
  return (u & 0x80000000u) ? ~u : (u | 0x80000000u);
}

// ---------- prep: 1/||p||, transpose W_lin ----------
__global__ void prep_kernel(const float* __restrict__ p, const float* __restrict__ W_lin,
                            float* __restrict__ pninv, float* __restrict__ wlt) {
  __shared__ float red[128];
  int t = threadIdx.x;  // 256
  if (t < 128) { float v = p[t]; red[t] = v * v; }
  __syncthreads();
  for (int s = 64; s > 0; s >>= 1) {
    if (t < s) red[t] += red[t + s];
    __syncthreads();
  }
  if (t == 0) pninv[0] = 1.0f / sqrtf(red[0]);
  for (int i = t; i < NF * NF; i += 256) {
    int r = i >> 7, c = i & 127;
    wlt[c * NF + r] = W_lin[i];
  }
}

// ---------- scores: one wave per row ----------
__global__ void score_kernel(const float* __restrict__ x, const float* __restrict__ p,
                             const float* __restrict__ pninv, float* __restrict__ score,
                             unsigned* __restrict__ keys, int n) {
  int wib = threadIdx.x >> 6, lane = threadIdx.x & 63;
  int r = blockIdx.x * 4 + wib;
  if (r >= n) return;
  float2 xv = *(const float2*)&x[(size_t)r * NF + lane * 2];
  float2 pv = *(const float2*)&p[lane * 2];
  float d = xv.x * pv.x + xv.y * pv.y;
#pragma unroll
  for (int off = 32; off > 0; off >>= 1) d += __shfl_down(d, off, 64);
  if (lane == 0) {
    float s = tanhf(d * pninv[0]);
    score[r] = s;
    keys[r] = okey(s);
  }
}

// ---------- top-128 radix select + stable sort, single block ----------
#define TK 128
#define LBCAP 2048
__global__ __launch_bounds__(1024) void topk_kernel(const unsigned* __restrict__ keys,
                                                    const float* __restrict__ score, int n,
                                                    int* __restrict__ perm, float* __restrict__ tsc) {
  __shared__ unsigned hist[256];
  __shared__ unsigned sh_prefix;
  __shared__ int sh_remaining;
  __shared__ int cntA, cntB;
  __shared__ unsigned selKey[TK];
  __shared__ int selIdx[TK];
  __shared__ int lbIdx[LBCAP];
  int t = threadIdx.x;
  if (t == 0) { sh_prefix = 0u; sh_remaining = TK; }
  for (int pos = 24; pos >= 0; pos -= 8) {
    if (t < 256) hist[t] = 0u;
    __syncthreads();
    unsigned pref = sh_prefix;
    unsigned hmask = (pos == 24) ? 0u : (0xFFFFFFFFu << (pos + 8));
    for (int i = t; i < n; i += 1024) {
      unsigned k = keys[i];
      if ((k & hmask) == pref) atomicAdd(&hist[(k >> pos) & 255], 1u);
    }
    __syncthreads();
    if (t == 0) {
      int rem = sh_remaining;
      unsigned c = 0;
      for (int b = 255; b >= 0; --b) {
        unsigned h = hist[b];
        if (c + h >= (unsigned)rem) {
          sh_prefix = pref | ((unsigned)b << pos);
          sh_remaining = rem - (int)c;
          break;
        }
        c += h;
      }
    }
    __syncthreads();
  }
  unsigned T = sh_prefix;
  int needEq = sh_remaining;
  if (t == 0) { cntA = 0; cntB = 0; }
  __syncthreads();
  for (int i = t; i < n; i += 1024) {
    unsigned k = keys[i];
    if (k > T) {
      int s = atomicAdd(&cntA, 1);
      if (s < TK) { selKey[s] = k; selIdx[s] = i; }
    } else if (k == T) {
      int s = atomicAdd(&cntB, 1);
      if (s < LBCAP) lbIdx[s] = i;
    }
  }
  __syncthreads();
  int nA = cntA;  // == TK - needEq
  int nb = cntB < LBCAP ? cntB : LBCAP;
  for (int ii = t; ii < nb; ii += 1024) {
    int my = lbIdx[ii];
    int rank = 0;
    for (int j = 0; j < nb; ++j) rank += (lbIdx[j] < my) ? 1 : 0;
    if (rank < needEq) { selKey[nA + rank] = T; selIdx[nA + rank] = my; }
  }
  __syncthreads();
  if (t < TK) {
    unsigned mk = selKey[t];
    int mi = selIdx[t];
    int rank = 0;
    for (int j = 0; j < TK; ++j) {
      unsigned kj = selKey[j];
      int ij = selIdx[j];
      rank += (kj > mk || (kj == mk && ij < mi)) ? 1 : 0;
    }
    perm[rank] = mi;
    tsc[rank] = score[mi];
  }
}

// ---------- GRU: block per row i, thread per col j ----------
__global__ void gru_kernel(const float* __restrict__ x, const int* __restrict__ perm,
                           const float* __restrict__ tsc, const float* __restrict__ W0,
                           const float* __restrict__ w_ih, const float* __restrict__ w_hh,
                           const float* __restrict__ b_ih, const float* __restrict__ b_hh,
                           float* __restrict__ W) {
  __shared__ float xs[NF], w0s[NF];
  int i = blockIdx.x, j = threadIdx.x;
  int pi = perm[i];
  float s = tsc[i];
  xs[j] = x[(size_t)pi * NF + j] * s;
  w0s[j] = W0[i * NF + j];
  __syncthreads();
  float gir = b_ih[j], giz = b_ih[NF + j], gin = b_ih[2 * NF + j];
  float ghr = b_hh[j], ghz = b_hh[NF + j], ghn = b_hh[2 * NF + j];
  const float* wr = w_ih + (size_t)j * NF;
  const float* wz = w_ih + (size_t)(NF + j) * NF;
  const float* wn = w_ih + (size_t)(2 * NF + j) * NF;
  const float* ur = w_hh + (size_t)j * NF;
  const float* uz = w_hh + (size_t)(NF + j) * NF;
  const float* un = w_hh + (size_t)(2 * NF + j) * NF;
#pragma unroll 4
  for (int k = 0; k < NF; ++k) {
    float xv = xs[k], wv = w0s[k];
    gir = fmaf(xv, wr[k], gir);
    giz = fmaf(xv, wz[k], giz);
    gin = fmaf(xv, wn[k], gin);
    ghr = fmaf(wv, ur[k], ghr);
    ghz = fmaf(wv, uz[k], ghz);
    ghn = fmaf(wv, un[k], ghn);
  }
  float r = 1.0f / (1.0f + expf(-(gir + ghr)));
  float z = 1.0f / (1.0f + expf(-(giz + ghz)));
  float nn = tanhf(gin + r * ghn);
  W[i * NF + j] = (1.0f - z) * nn + z * w0s[j];
}

// ---------- init: deg=1 (self-loop), cnt=0, cursor=0 ----------
__global__ void init_kernel(float* __restrict__ deg, int* __restrict__ cnt,
                            int* __restrict__ cursor, int n) {
  int i = blockIdx.x * blockDim.x + threadIdx.x;
  if (i < n) { deg[i] = 1.0f; cnt[i] = 0; cursor[i] = 0; }
}

// ---------- histogram of in-degree + weighted degree ----------
__global__ void hist_deg_kernel(const int* __restrict__ ei, const float* __restrict__ ew,
                                int* __restrict__ cnt, float* __restrict__ deg, int E) {
  int e = blockIdx.x * blockDim.x + threadIdx.x;
  if (e < E) {
    int c = ei[E + e];
    atomicAdd(&cnt[c], 1);
    unsafeAtomicAdd(&deg[c], ew[e]);
  }
}

__global__ void dinv_kernel(const float* __restrict__ deg, float* __restrict__ dinv, int n) {
  int i = blockIdx.x * blockDim.x + threadIdx.x;
  if (i < n) {
    float d = deg[i];
    dinv[i] = (d > 0.0f) ? (1.0f / sqrtf(d)) : 0.0f;
  }
}

// ---------- exclusive scan over cnt -> off ----------
#define SCAN_B 1024
__global__ __launch_bounds__(1024) void scan1_kernel(const int* __restrict__ cnt,
                                                     int* __restrict__ off,
                                                     int* __restrict__ bsum, int n) {
  __shared__ int sd[SCAN_B];
  int t = threadIdx.x;
  int i = blockIdx.x * SCAN_B + t;
  int v = (i < n) ? cnt[i] : 0;
  sd[t] = v;
  __syncthreads();
  for (int s = 1; s < SCAN_B; s <<= 1) {
    int add = (t >= s) ? sd[t - s] : 0;
    __syncthreads();
    sd[t] += add;
    __syncthreads();
  }
  if (i < n) off[i] = sd[t] - v;  // exclusive
  if (t == SCAN_B - 1) bsum[blockIdx.x] = sd[t];
}
__global__ void scan2_kernel(const int* __restrict__ bsum, int* __restrict__ bexc, int nb) {
  if (threadIdx.x == 0 && blockIdx.x == 0) {
    int run = 0;
    for (int b = 0; b < nb; ++b) { bexc[b] = run; run += bsum[b]; }
    bexc[nb] = run;
  }
}
__global__ void scan3_kernel(int* __restrict__ off, const int* __restrict__ bexc, int n, int nb) {
  int i = blockIdx.x * blockDim.x + threadIdx.x;
  if (i < n) off[i] += bexc[i >> 10];
  else if (i == n) off[n] = bexc[nb];
}

// ---------- fill CSR: (row, coef) per incoming edge, grouped by col ----------
__global__ void fill_kernel(const int* __restrict__ ei, const float* __restrict__ ew,
                            const float* __restrict__ dinv, const int* __restrict__ off,
                            int* __restrict__ cursor, int* __restrict__ erow,
                            float* __restrict__ ecoef, int E) {
  int e = blockIdx.x * blockDim.x + threadIdx.x;
  if (e >= E) return;
  int r = ei[e], c = ei[E + e];
  int pos = off[c] + atomicAdd(&cursor[c], 1);
  erow[pos] = r;
  ecoef[pos] = dinv[r] * ew[e] * dinv[c];
}

// ---------- aggregate: one wave per node, atomic-free ----------
__global__ void aggregate_kernel(const int* __restrict__ erow, const float* __restrict__ ecoef,
                                 const int* __restrict__ off, const float* __restrict__ dinv,
                                 const float* __restrict__ xw, float* __restrict__ h, int n) {
  int w = (int)((blockIdx.x * (size_t)blockDim.x + threadIdx.x) >> 6);
  int lane = threadIdx.x & 63;
  if (w >= n) return;
  int n0 = off[w], n1 = off[w + 1];
  float dv = dinv[w];
  float c2 = dv * dv;  // self-loop: dinv[i]*1.0*dinv[i]
  float2 xv = *(const float2*)&xw[(size_t)w * NF + lane * 2];
  float2 acc = make_float2(c2 * xv.x, c2 * xv.y);
  for (int e = n0; e < n1; ++e) {
    int r = erow[e];
    float cf = ecoef[e];
    float2 v = *(const float2*)&xw[(size_t)r * NF + lane * 2];
    acc.x = fmaf(cf, v.x, acc.x);
    acc.y = fmaf(cf, v.y, acc.y);
  }
  *(float2*)&h[(size_t)w * NF + lane * 2] = acc;
}

// ---------- GEMM: C[r,c] = sum_k op(A[r,k]) * B[k,c] (+bias), B is 128x128 ----------
template <int RELU, int BIAS>
__global__ __launch_bounds__(256) void gemm128_kernel(const float* __restrict__ A,
                                                      const float* __restrict__ Bm,
                                                      const float* __restrict__ bias,
                                                      float* __restrict__ C, int nrows) {
  __shared__ float Bs[64][128];
  __shared__ float As[64][68];  // [k][r], padded
  const int t = threadIdx.x;
  const int ct = t & 31;   // 4-col group
  const int rt = t >> 5;   // 0..7 -> rows rt*8..rt*8+7
  const int row0 = blockIdx.x * 64;
  float4 acc[8];
#pragma unroll
  for (int j = 0; j < 8; ++j) acc[j] = make_float4(0.f, 0.f, 0.f, 0.f);

  for (int ph = 0; ph < 2; ++ph) {
    {
      const float4* B4 = (const float4*)(Bm + ph * 64 * NF);
#pragma unroll
      for (int pp = 0; pp < 8; ++pp) {
        int idx = pp * 256 + t;  // 0..2047
        int k = idx >> 5, c4 = idx & 31;
        *((float4*)&Bs[k][c4 * 4]) = B4[idx];
      }
    }
    {
#pragma unroll
      for (int pp = 0; pp < 4; ++pp) {
        int idx = pp * 256 + t;  // 0..1023
        int r = idx >> 4;        // 0..63
        int k4 = idx & 15;       // col group
        int gr = row0 + r;
        float4 v = make_float4(0.f, 0.f, 0.f, 0.f);
        if (gr < nrows) v = *((const float4*)&A[(size_t)gr * NF + ph * 64 + k4 * 4]);
        if (RELU) {
          v.x = fmaxf(v.x, 0.f); v.y = fmaxf(v.y, 0.f);
          v.z = fmaxf(v.z, 0.f); v.w = fmaxf(v.w, 0.f);
        }
        As[k4 * 4 + 0][r] = v.x;
        As[k4 * 4 + 1][r] = v.y;
        As[k4 * 4 + 2][r] = v.z;
        As[k4 * 4 + 3][r] = v.w;
      }
    }
    __syncthreads();
#pragma unroll 4
    for (int k = 0; k < 64; ++k) {
      float4 b = *((const float4*)&Bs[k][ct * 4]);
      float a[8];
      *((float4*)&a[0]) = *((const float4*)&As[k][rt * 8]);
      *((float4*)&a[4]) = *((const float4*)&As[k][rt * 8 + 4]);
#pragma unroll
      for (int j = 0; j < 8; ++j) {
        acc[j].x = fmaf(a[j], b.x, acc[j].x);
        acc[j].y = fmaf(a[j], b.y, acc[j].y);
        acc[j].z = fmaf(a[j], b.z, acc[j].z);
        acc[j].w = fmaf(a[j], b.w, acc[j].w);
      }
    }
    __syncthreads();
  }
  float4 bv = make_float4(0.f, 0.f, 0.f, 0.f);
  if (BIAS) bv = *((const float4*)&bias[ct * 4]);
#pragma unroll
  for (int j = 0; j < 8; ++j) {
    int gr = row0 + rt * 8 + j;
    if (gr < nrows) {
      float4 o = acc[j];
      if (BIAS) { o.x += bv.x; o.y += bv.y; o.z += bv.z; o.w += bv.w; }
      *((float4*)&C[(size_t)gr * NF + ct * 4]) = o;
    }
  }
}

extern "C" void kernel_launch(void* const* d_in, const int* in_sizes, int n_in,
                              void* d_out, int out_size, void* d_ws, size_t ws_size,
                              hipStream_t stream) {
  const float* x = (const float*)d_in[0];
  const int* ei = (const int*)d_in[1];
  const float* ew = (const float*)d_in[2];
  const float* p = (const float*)d_in[3];
  const float* w_ih = (const float*)d_in[4];
  const float* w_hh = (const float*)d_in[5];
  const float* b_ih = (const float*)d_in[6];
  const float* b_hh = (const float*)d_in[7];
  const float* W0 = (const float*)d_in[8];
  const float* W_lin = (const float*)d_in[9];
  const float* b_lin = (const float*)d_in[10];
  float* out = (float*)d_out;

  const int N = in_sizes[0] / NF;  // 50000
  const int E = in_sizes[1] / 2;   // 800000

  char* w = (char*)d_ws;
  float* xw = (float*)w;                                    // N*128
  float* score = (float*)(w + (size_t)N * NF * 4);          // N
  unsigned* keys = (unsigned*)(score + N);                  // N
  float* deg = (float*)(keys + N);                          // N
  float* dinv = deg + N;                                    // N
  int* cnt = (int*)(dinv + N);                              // N
  int* cursor = cnt + N;                                    // N
  int* off = cursor + N;                                    // N+1
  int* bsum = off + N + 1;                                  // 1024
  int* bexc = bsum + 1024;                                  // 1024+1
  int* erow = bexc + 1025;                                  // E
  float* ecoef = (float*)(erow + E);                        // E
  float* Wev = ecoef + E;                                   // 128*128
  float* wlt = Wev + NF * NF;                               // 128*128
  int* perm = (int*)(wlt + NF * NF);                        // 128
  float* tsc = (float*)(perm + NF);                         // 128
  float* pninv = tsc + NF;                                  // 1

  const int nb = (N + SCAN_B - 1) / SCAN_B;

  prep_kernel<<<1, 256, 0, stream>>>(p, W_lin, pninv, wlt);
  score_kernel<<<(N + 3) / 4, 256, 0, stream>>>(x, p, pninv, score, keys, N);
  topk_kernel<<<1, 1024, 0, stream>>>(keys, score, N, perm, tsc);
  gru_kernel<<<NF, NF, 0, stream>>>(x, perm, tsc, W0, w_ih, w_hh, b_ih, b_hh, Wev);
  init_kernel<<<(N + 255) / 256, 256, 0, stream>>>(deg, cnt, cursor, N);
  hist_deg_kernel<<<(E + 255) / 256, 256, 0, stream>>>(ei, ew, cnt, deg, E);
  dinv_kernel<<<(N + 255) / 256, 256, 0, stream>>>(deg, dinv, N);
  scan1_kernel<<<nb, SCAN_B, 0, stream>>>(cnt, off, bsum, N);
  scan2_kernel<<<1, 64, 0, stream>>>(bsum, bexc, nb);
  scan3_kernel<<<(N + 256) / 256, 256, 0, stream>>>(off, bexc, N, nb);
  fill_kernel<<<(E + 255) / 256, 256, 0, stream>>>(ei, ew, dinv, off, cursor, erow, ecoef, E);
  gemm128_kernel<0, 0><<<(N + 63) / 64, 256, 0, stream>>>(x, Wev, nullptr, xw, N);
  aggregate_kernel<<<(N + 3) / 4, 256, 0, stream>>>(erow, ecoef, off, dinv, xw, out, N);
  gemm128_kernel<1, 1><<<(N + 63) / 64, 256, 0, stream>>>(out, wlt, b_lin, out, N);
}